// Round 1
// baseline (911.551 us; speedup 1.0000x reference)
//
#include <hip/hip_runtime.h>
#include <cstdint>
#include <cmath>

typedef __bf16 bf16_t;
typedef __bf16 bf16x8 __attribute__((ext_vector_type(8)));
typedef float f32x4 __attribute__((ext_vector_type(4)));

// ---- async global->LDS (width=16). LDS dest must be wave-uniform base + lane*16.
__device__ __forceinline__ void gload_lds16(const void* gptr, void* ldsptr) {
    __builtin_amdgcn_global_load_lds(
        (__attribute__((address_space(1))) void*)(const_cast<void*>(gptr)),
        (__attribute__((address_space(3))) void*)ldsptr,
        16, 0, 0);
}

// ---- transpose [K][N] fp32 -> [N][K] bf16 (for gemm_bt B-operand)
__global__ __launch_bounds__(256)
void transpose_to_bf16(const float* __restrict__ W, bf16_t* __restrict__ Wt,
                       int K, int N) {
    __shared__ float tile[32][33];
    const int bx = blockIdx.x;           // N / 32
    const int by = blockIdx.y;           // K / 32
    const int c  = threadIdx.x & 31;
    const int r0 = threadIdx.x >> 5;     // 0..7
#pragma unroll
    for (int i = 0; i < 4; i++) {
        int r = r0 + i * 8;
        tile[r][c] = W[(size_t)(by * 32 + r) * N + bx * 32 + c];
    }
    __syncthreads();
#pragma unroll
    for (int i = 0; i < 4; i++) {
        int r = r0 + i * 8;
        Wt[(size_t)(bx * 32 + r) * K + by * 32 + c] = (bf16_t)tile[c][r];
    }
}

// ---- PNA aggregation: x[B][128][256] -> h[B][3072] bf16
// h = [mean,max,min,std | same*ampS | same*attS]
__global__ __launch_bounds__(256)
void agg_kernel(const float* __restrict__ x, bf16_t* __restrict__ h,
                float ampS, float attS) {
    const int b    = blockIdx.x;
    const int tid  = threadIdx.x;
    const int g    = tid >> 6;     // 0..3
    const int lane = tid & 63;

    const float4* xb = (const float4*)(x + (size_t)b * 128 * 256);

    float4 sum = make_float4(0.f, 0.f, 0.f, 0.f);
    float4 sq  = make_float4(0.f, 0.f, 0.f, 0.f);
    float4 mx  = make_float4(-3.402823466e38f, -3.402823466e38f,
                             -3.402823466e38f, -3.402823466e38f);
    float4 mn  = make_float4(3.402823466e38f, 3.402823466e38f,
                             3.402823466e38f, 3.402823466e38f);

    for (int n = g; n < 128; n += 4) {
        float4 v = xb[n * 64 + lane];
        sum.x += v.x; sum.y += v.y; sum.z += v.z; sum.w += v.w;
        sq.x += v.x * v.x; sq.y += v.y * v.y; sq.z += v.z * v.z; sq.w += v.w * v.w;
        mx.x = fmaxf(mx.x, v.x); mx.y = fmaxf(mx.y, v.y);
        mx.z = fmaxf(mx.z, v.z); mx.w = fmaxf(mx.w, v.w);
        mn.x = fminf(mn.x, v.x); mn.y = fminf(mn.y, v.y);
        mn.z = fminf(mn.z, v.z); mn.w = fminf(mn.w, v.w);
    }

    __shared__ float4 ssum[256], ssq[256], smx[256], smn[256];
    ssum[tid] = sum; ssq[tid] = sq; smx[tid] = mx; smn[tid] = mn;
    __syncthreads();

    __shared__ float s_aggr[1024];
    if (g == 0) {
#pragma unroll
        for (int k = 1; k < 4; k++) {
            float4 a = ssum[lane + 64 * k];
            sum.x += a.x; sum.y += a.y; sum.z += a.z; sum.w += a.w;
            float4 q = ssq[lane + 64 * k];
            sq.x += q.x; sq.y += q.y; sq.z += q.z; sq.w += q.w;
            float4 c4 = smx[lane + 64 * k];
            mx.x = fmaxf(mx.x, c4.x); mx.y = fmaxf(mx.y, c4.y);
            mx.z = fmaxf(mx.z, c4.z); mx.w = fmaxf(mx.w, c4.w);
            float4 d4 = smn[lane + 64 * k];
            mn.x = fminf(mn.x, d4.x); mn.y = fminf(mn.y, d4.y);
            mn.z = fminf(mn.z, d4.z); mn.w = fminf(mn.w, d4.w);
        }
        float sums[4] = {sum.x, sum.y, sum.z, sum.w};
        float sqs[4]  = {sq.x, sq.y, sq.z, sq.w};
        float mxs[4]  = {mx.x, mx.y, mx.z, mx.w};
        float mns[4]  = {mn.x, mn.y, mn.z, mn.w};
#pragma unroll
        for (int c = 0; c < 4; c++) {
            int d = lane * 4 + c;
            float mean = sums[c] * (1.0f / 128.0f);
            float var  = (sqs[c] - sums[c] * sums[c] * (1.0f / 128.0f)) * (1.0f / 127.0f);
            var = fmaxf(var, 0.f);
            s_aggr[d]       = mean;
            s_aggr[256 + d] = mxs[c];
            s_aggr[512 + d] = mns[c];
            s_aggr[768 + d] = sqrtf(var);
        }
    }
    __syncthreads();

    const size_t hb = (size_t)b * 3072;
#pragma unroll
    for (int j = 0; j < 12; j++) {
        int col = tid + j * 256;
        int seg = col >> 10;                       // 0: aggr, 1: amp, 2: att
        float scale = (seg == 0) ? 1.0f : ((seg == 1) ? ampS : attS);
        h[hb + col] = (bf16_t)(s_aggr[col & 1023] * scale);
    }
}

// ---- m97-style bf16 GEMM:  C[M][N] = A[M][K] @ Bt[N][K]^T + bias
// Block tile BM x BN, BK=32, 256 threads = 4 waves in 2x2, each wave MTx NT
// 16x16 subtiles. RELU_BF16: relu + bf16 store; else fp32 store.
template <int BM, int BN, int MT, int NT, bool RELU_BF16>
__global__ __launch_bounds__(256, 2)
void gemm_bt(const bf16_t* __restrict__ A, const bf16_t* __restrict__ Bt,
             const float* __restrict__ bias, void* __restrict__ Cout,
             int M, int N, int K) {
    constexpr int BK = 32;
    __shared__ bf16_t As[BM * BK];   // [row][k], unpadded (global_load_lds req.)
    __shared__ bf16_t Bs[BN * BK];

    const int tid   = threadIdx.x;
    const int lane  = tid & 63;
    const int quad  = lane >> 4;
    const int l16   = lane & 15;
    const int wid   = tid >> 6;
    const int waveM = wid >> 1;      // 0..1
    const int waveN = wid & 1;       // 0..1
    const int m0    = blockIdx.y * BM;
    const int n0    = blockIdx.x * BN;

    f32x4 acc[MT][NT];
#pragma unroll
    for (int i = 0; i < MT; i++)
#pragma unroll
        for (int j = 0; j < NT; j++)
            acc[i][j] = f32x4{0.f, 0.f, 0.f, 0.f};

    constexpr int nchA = BM * 4;     // 16B chunks in A tile
    constexpr int nchB = BN * 4;

    for (int k0 = 0; k0 < K; k0 += BK) {
        __syncthreads();   // previous tile fully consumed
#pragma unroll
        for (int c = tid; c < nchA; c += 256) {
            int row = c >> 2, part = c & 3;
            gload_lds16(A + (size_t)(m0 + row) * K + k0 + part * 8,
                        (char*)As + (size_t)c * 16);
        }
#pragma unroll
        for (int c = tid; c < nchB; c += 256) {
            int row = c >> 2, part = c & 3;
            gload_lds16(Bt + (size_t)(n0 + row) * K + k0 + part * 8,
                        (char*)Bs + (size_t)c * 16);
        }
        __syncthreads();   // drains vmcnt -> staging visible

        bf16x8 af[MT], bfr[NT];
#pragma unroll
        for (int mt = 0; mt < MT; mt++)
            af[mt] = *(const bf16x8*)&As[(waveM * MT * 16 + mt * 16 + l16) * BK + quad * 8];
#pragma unroll
        for (int nt = 0; nt < NT; nt++)
            bfr[nt] = *(const bf16x8*)&Bs[(waveN * NT * 16 + nt * 16 + l16) * BK + quad * 8];
#pragma unroll
        for (int mt = 0; mt < MT; mt++)
#pragma unroll
            for (int nt = 0; nt < NT; nt++)
                acc[mt][nt] = __builtin_amdgcn_mfma_f32_16x16x32_bf16(
                    af[mt], bfr[nt], acc[mt][nt], 0, 0, 0);
    }

    // Epilogue: C/D layout col=lane&15, row=quad*4+reg (m89/m91 verified)
    const int rowbase = m0 + waveM * MT * 16;
    const int colbase = n0 + waveN * NT * 16;
#pragma unroll
    for (int mt = 0; mt < MT; mt++) {
#pragma unroll
        for (int nt = 0; nt < NT; nt++) {
            int col = colbase + nt * 16 + l16;
            float bv = bias[col];
#pragma unroll
            for (int r = 0; r < 4; r++) {
                int row = rowbase + mt * 16 + quad * 4 + r;
                float v = acc[mt][nt][r] + bv;
                if (RELU_BF16) {
                    v = v > 0.f ? v : 0.f;
                    ((bf16_t*)Cout)[(size_t)row * N + col] = (bf16_t)v;
                } else {
                    ((float*)Cout)[(size_t)row * N + col] = v;
                }
            }
        }
    }
}

extern "C" void kernel_launch(void* const* d_in, const int* in_sizes, int n_in,
                              void* d_out, int out_size, void* d_ws, size_t ws_size,
                              hipStream_t stream) {
    const float* x  = (const float*)d_in[0];   // [4096][128][256]
    const float* W1 = (const float*)d_in[1];   // [3072][4096]
    const float* b1 = (const float*)d_in[2];   // [4096]
    const float* W2 = (const float*)d_in[3];   // [4096][256]
    const float* b2 = (const float*)d_in[4];   // [256]
    float* out = (float*)d_out;                // [4096][256]

    const int B = 4096, D = 256, H = 4096, O = 256;
    const int K1 = 12 * D;                     // 3072

    char* ws = (char*)d_ws;
    size_t off = 0;
    bf16_t* W1t = (bf16_t*)(ws + off); off += (size_t)H * K1 * 2;   // [H][K1]
    bf16_t* W2t = (bf16_t*)(ws + off); off += (size_t)O * H * 2;    // [O][H]
    bf16_t* h   = (bf16_t*)(ws + off); off += (size_t)B * K1 * 2;   // [B][K1]
    bf16_t* h2  = (bf16_t*)(ws + off); off += (size_t)B * H * 2;    // [B][H]
    (void)ws_size; (void)in_sizes; (void)n_in; (void)out_size;

    // weights -> bf16, transposed to [N][K] for gemm_bt
    transpose_to_bf16<<<dim3(H / 32, K1 / 32), 256, 0, stream>>>(W1, W1t, K1, H);
    transpose_to_bf16<<<dim3(O / 32, H / 32), 256, 0, stream>>>(W2, W2t, H, O);

    const float ampS = (float)(log(1025.0) / 3.0);   // log(4D+1)/DELTA
    const float attS = (float)(3.0 / log(1025.0));   // DELTA/log(4D+1)

    agg_kernel<<<B, 256, 0, stream>>>(x, h, ampS, attS);

    // h2 = relu(h @ W1 + b1), bf16
    gemm_bt<128, 128, 4, 4, true>
        <<<dim3(H / 128, B / 128), 256, 0, stream>>>(h, W1t, b1, h2, B, H, K1);

    // out = h2 @ W2 + b2, fp32
    gemm_bt<64, 64, 2, 2, false>
        <<<dim3(O / 64, B / 64), 256, 0, stream>>>(h2, W2t, b2, out, B, O, H);
}

// Round 2
// 796.673 us; speedup vs baseline: 1.1442x; 1.1442x over previous
//
#include <hip/hip_runtime.h>
#include <cstdint>
#include <cmath>

typedef __bf16 bf16_t;
typedef __bf16 bf16x8 __attribute__((ext_vector_type(8)));
typedef float f32x4 __attribute__((ext_vector_type(4)));

// ---- async global->LDS (width=16). LDS dest must be wave-uniform base + lane*16.
__device__ __forceinline__ void gload_lds16(const void* gptr, void* ldsptr) {
    __builtin_amdgcn_global_load_lds(
        (__attribute__((address_space(1))) void*)(const_cast<void*>(gptr)),
        (__attribute__((address_space(3))) void*)ldsptr,
        16, 0, 0);
}

// ---- W1eff build: W1[3072][H] fp32 -> Wt[H][1024] bf16 where
//   Wt[n][k] = W1[k][n] + ampS*W1[1024+k][n] + attS*W1[2048+k][n]
__global__ __launch_bounds__(256)
void build_w1eff(const float* __restrict__ W1, bf16_t* __restrict__ Wt,
                 int H, float ampS, float attS) {
    __shared__ float tile[32][33];
    const int bx = blockIdx.x;           // H / 32   (n tiles)
    const int by = blockIdx.y;           // 1024/32  (k tiles)
    const int c  = threadIdx.x & 31;
    const int r0 = threadIdx.x >> 5;     // 0..7
#pragma unroll
    for (int i = 0; i < 4; i++) {
        int r = r0 + i * 8;
        size_t kk = (size_t)(by * 32 + r);
        size_t col = (size_t)bx * 32 + c;
        float v0 = W1[kk * H + col];
        float v1 = W1[(kk + 1024) * H + col];
        float v2 = W1[(kk + 2048) * H + col];
        tile[r][c] = v0 + ampS * v1 + attS * v2;
    }
    __syncthreads();
#pragma unroll
    for (int i = 0; i < 4; i++) {
        int r = r0 + i * 8;
        Wt[(size_t)(bx * 32 + r) * 1024 + by * 32 + c] = (bf16_t)tile[c][r];
    }
}

// ---- transpose [K][N] fp32 -> [N][K] bf16 (for gemm_bt B-operand)
__global__ __launch_bounds__(256)
void transpose_to_bf16(const float* __restrict__ W, bf16_t* __restrict__ Wt,
                       int K, int N) {
    __shared__ float tile[32][33];
    const int bx = blockIdx.x;           // N / 32
    const int by = blockIdx.y;           // K / 32
    const int c  = threadIdx.x & 31;
    const int r0 = threadIdx.x >> 5;
#pragma unroll
    for (int i = 0; i < 4; i++) {
        int r = r0 + i * 8;
        tile[r][c] = W[(size_t)(by * 32 + r) * N + bx * 32 + c];
    }
    __syncthreads();
#pragma unroll
    for (int i = 0; i < 4; i++) {
        int r = r0 + i * 8;
        Wt[(size_t)(bx * 32 + r) * K + by * 32 + c] = (bf16_t)tile[c][r];
    }
}

// ---- PNA aggregation: x[B][128][256] -> aggr[B][1024] bf16 = [mean,max,min,std]
__global__ __launch_bounds__(256)
void agg_kernel(const float* __restrict__ x, bf16_t* __restrict__ h) {
    const int b    = blockIdx.x;
    const int tid  = threadIdx.x;
    const int g    = tid >> 6;     // 0..3
    const int lane = tid & 63;

    const float4* xb = (const float4*)(x + (size_t)b * 128 * 256);

    float4 sum = make_float4(0.f, 0.f, 0.f, 0.f);
    float4 sq  = make_float4(0.f, 0.f, 0.f, 0.f);
    float4 mx  = make_float4(-3.402823466e38f, -3.402823466e38f,
                             -3.402823466e38f, -3.402823466e38f);
    float4 mn  = make_float4(3.402823466e38f, 3.402823466e38f,
                             3.402823466e38f, 3.402823466e38f);

    for (int n = g; n < 128; n += 4) {
        float4 v = xb[n * 64 + lane];
        sum.x += v.x; sum.y += v.y; sum.z += v.z; sum.w += v.w;
        sq.x += v.x * v.x; sq.y += v.y * v.y; sq.z += v.z * v.z; sq.w += v.w * v.w;
        mx.x = fmaxf(mx.x, v.x); mx.y = fmaxf(mx.y, v.y);
        mx.z = fmaxf(mx.z, v.z); mx.w = fmaxf(mx.w, v.w);
        mn.x = fminf(mn.x, v.x); mn.y = fminf(mn.y, v.y);
        mn.z = fminf(mn.z, v.z); mn.w = fminf(mn.w, v.w);
    }

    __shared__ float4 ssum[256], ssq[256], smx[256], smn[256];
    ssum[tid] = sum; ssq[tid] = sq; smx[tid] = mx; smn[tid] = mn;
    __syncthreads();

    __shared__ float s_aggr[1024];
    if (g == 0) {
#pragma unroll
        for (int k = 1; k < 4; k++) {
            float4 a = ssum[lane + 64 * k];
            sum.x += a.x; sum.y += a.y; sum.z += a.z; sum.w += a.w;
            float4 q = ssq[lane + 64 * k];
            sq.x += q.x; sq.y += q.y; sq.z += q.z; sq.w += q.w;
            float4 c4 = smx[lane + 64 * k];
            mx.x = fmaxf(mx.x, c4.x); mx.y = fmaxf(mx.y, c4.y);
            mx.z = fmaxf(mx.z, c4.z); mx.w = fmaxf(mx.w, c4.w);
            float4 d4 = smn[lane + 64 * k];
            mn.x = fminf(mn.x, d4.x); mn.y = fminf(mn.y, d4.y);
            mn.z = fminf(mn.z, d4.z); mn.w = fminf(mn.w, d4.w);
        }
        float sums[4] = {sum.x, sum.y, sum.z, sum.w};
        float sqs[4]  = {sq.x, sq.y, sq.z, sq.w};
        float mxs[4]  = {mx.x, mx.y, mx.z, mx.w};
        float mns[4]  = {mn.x, mn.y, mn.z, mn.w};
#pragma unroll
        for (int c = 0; c < 4; c++) {
            int d = lane * 4 + c;
            float mean = sums[c] * (1.0f / 128.0f);
            float var  = (sqs[c] - sums[c] * sums[c] * (1.0f / 128.0f)) * (1.0f / 127.0f);
            var = fmaxf(var, 0.f);
            s_aggr[d]       = mean;
            s_aggr[256 + d] = mxs[c];
            s_aggr[512 + d] = mns[c];
            s_aggr[768 + d] = sqrtf(var);
        }
    }
    __syncthreads();

    const size_t hb = (size_t)b * 1024;
#pragma unroll
    for (int j = 0; j < 4; j++) {
        int col = tid + j * 256;
        h[hb + col] = (bf16_t)s_aggr[col];
    }
}

// ---- m97-style bf16 GEMM:  C[M][N] = A[M][K] @ Bt[N][K]^T (+ bias)
// MODE 0: fp32 store + bias; MODE 1: relu + bf16 store + bias;
// MODE 2: fp32 partial store (split-K, no bias), C += z*M*N.
template <int BM, int BN, int MT, int NT, int MODE>
__global__ __launch_bounds__(256, 2)
void gemm_bt(const bf16_t* __restrict__ A, const bf16_t* __restrict__ Bt,
             const float* __restrict__ bias, void* __restrict__ Cout,
             int M, int N, int K, int Kc) {
    constexpr int BK = 32;
    __shared__ bf16_t As[BM * BK];   // [row][k], unpadded (global_load_lds req.)
    __shared__ bf16_t Bs[BN * BK];

    const int tid   = threadIdx.x;
    const int lane  = tid & 63;
    const int quad  = lane >> 4;
    const int l16   = lane & 15;
    const int wid   = tid >> 6;
    const int waveM = wid >> 1;      // 0..1
    const int waveN = wid & 1;       // 0..1
    const int m0    = blockIdx.y * BM;
    const int n0    = blockIdx.x * BN;
    const int kz    = (MODE == 2) ? blockIdx.z : 0;
    const int kbeg  = kz * Kc;
    const int kend  = (MODE == 2) ? (kbeg + Kc) : K;

    f32x4 acc[MT][NT];
#pragma unroll
    for (int i = 0; i < MT; i++)
#pragma unroll
        for (int j = 0; j < NT; j++)
            acc[i][j] = f32x4{0.f, 0.f, 0.f, 0.f};

    constexpr int nchA = BM * 4;     // 16B chunks in A tile
    constexpr int nchB = BN * 4;

    for (int k0 = kbeg; k0 < kend; k0 += BK) {
        __syncthreads();
#pragma unroll
        for (int c = tid; c < nchA; c += 256) {
            int row = c >> 2, part = c & 3;
            gload_lds16(A + (size_t)(m0 + row) * K + k0 + part * 8,
                        (char*)As + (size_t)c * 16);
        }
#pragma unroll
        for (int c = tid; c < nchB; c += 256) {
            int row = c >> 2, part = c & 3;
            gload_lds16(Bt + (size_t)(n0 + row) * K + k0 + part * 8,
                        (char*)Bs + (size_t)c * 16);
        }
        __syncthreads();

        bf16x8 af[MT], bfr[NT];
#pragma unroll
        for (int mt = 0; mt < MT; mt++)
            af[mt] = *(const bf16x8*)&As[(waveM * MT * 16 + mt * 16 + l16) * BK + quad * 8];
#pragma unroll
        for (int nt = 0; nt < NT; nt++)
            bfr[nt] = *(const bf16x8*)&Bs[(waveN * NT * 16 + nt * 16 + l16) * BK + quad * 8];
#pragma unroll
        for (int mt = 0; mt < MT; mt++)
#pragma unroll
            for (int nt = 0; nt < NT; nt++)
                acc[mt][nt] = __builtin_amdgcn_mfma_f32_16x16x32_bf16(
                    af[mt], bfr[nt], acc[mt][nt], 0, 0, 0);
    }

    // Epilogue: C/D layout col=lane&15, row=quad*4+reg
    const int rowbase = m0 + waveM * MT * 16;
    const int colbase = n0 + waveN * NT * 16;
    float* Cp = (MODE == 2) ? ((float*)Cout + (size_t)kz * M * N) : (float*)Cout;
#pragma unroll
    for (int mt = 0; mt < MT; mt++) {
#pragma unroll
        for (int nt = 0; nt < NT; nt++) {
            int col = colbase + nt * 16 + l16;
            float bv = (MODE == 2) ? 0.f : bias[col];
#pragma unroll
            for (int r = 0; r < 4; r++) {
                int row = rowbase + mt * 16 + quad * 4 + r;
                float v = acc[mt][nt][r] + bv;
                if (MODE == 1) {
                    v = v > 0.f ? v : 0.f;
                    ((bf16_t*)Cout)[(size_t)row * N + col] = (bf16_t)v;
                } else {
                    Cp[(size_t)row * N + col] = v;
                }
            }
        }
    }
}

// ---- split-K reduce: out[i] = sum_z part[z][i] + b2[i % N], float4-wide
__global__ __launch_bounds__(256)
void reduce_splitk(const float* __restrict__ part, const float* __restrict__ b2,
                   float* __restrict__ out, int total4, int n4, int Z) {
    int f = blockIdx.x * 256 + threadIdx.x;
    if (f >= total4) return;
    const float4* p = (const float4*)part;
    float4 acc = p[f];
    for (int z = 1; z < Z; z++) {
        float4 v = p[(size_t)z * total4 + f];
        acc.x += v.x; acc.y += v.y; acc.z += v.z; acc.w += v.w;
    }
    float4 bv = ((const float4*)b2)[f & (n4 - 1)];
    acc.x += bv.x; acc.y += bv.y; acc.z += bv.z; acc.w += bv.w;
    ((float4*)out)[f] = acc;
}

extern "C" void kernel_launch(void* const* d_in, const int* in_sizes, int n_in,
                              void* d_out, int out_size, void* d_ws, size_t ws_size,
                              hipStream_t stream) {
    const float* x  = (const float*)d_in[0];   // [4096][128][256]
    const float* W1 = (const float*)d_in[1];   // [3072][4096]
    const float* b1 = (const float*)d_in[2];   // [4096]
    const float* W2 = (const float*)d_in[3];   // [4096][256]
    const float* b2 = (const float*)d_in[4];   // [256]
    float* out = (float*)d_out;                // [4096][256]

    const int B = 4096, H = 4096, O = 256;
    const int K1 = 1024;                       // effective K after weight folding
    const int ZSPLIT = 4, KC = H / ZSPLIT;     // gemm2 split-K

    char* ws = (char*)d_ws;
    size_t off = 0;
    bf16_t* W1t  = (bf16_t*)(ws + off); off += (size_t)H * K1 * 2;        // [H][1024]
    bf16_t* W2t  = (bf16_t*)(ws + off); off += (size_t)O * H * 2;         // [O][H]
    bf16_t* aggr = (bf16_t*)(ws + off); off += (size_t)B * K1 * 2;        // [B][1024]
    bf16_t* h2   = (bf16_t*)(ws + off); off += (size_t)B * H * 2;         // [B][H]
    float*  part = (float*)(ws + off);  off += (size_t)ZSPLIT * B * O * 4;
    (void)ws_size; (void)in_sizes; (void)n_in; (void)out_size;

    const float ampS = (float)(log(1025.0) / 3.0);   // log(4D+1)/DELTA
    const float attS = (float)(3.0 / log(1025.0));   // DELTA/log(4D+1)

    // W1eff = W1[0:1024] + ampS*W1[1024:2048] + attS*W1[2048:3072], ->[H][1024] bf16
    build_w1eff<<<dim3(H / 32, K1 / 32), 256, 0, stream>>>(W1, W1t, H, ampS, attS);
    transpose_to_bf16<<<dim3(O / 32, H / 32), 256, 0, stream>>>(W2, W2t, H, O);

    agg_kernel<<<B, 256, 0, stream>>>(x, aggr);

    // h2 = relu(aggr @ W1eff + b1), bf16
    gemm_bt<128, 128, 4, 4, 1>
        <<<dim3(H / 128, B / 128), 256, 0, stream>>>(aggr, W1t, b1, h2, B, H, K1, 0);

    // part[z] = h2[:, z*KC:(z+1)*KC] @ W2t[:, same]^T  (split-K, 1024 blocks)
    gemm_bt<64, 64, 2, 2, 2>
        <<<dim3(O / 64, B / 64, ZSPLIT), 256, 0, stream>>>(h2, W2t, nullptr, part,
                                                           B, O, H, KC);

    // out = sum_z part[z] + b2
    const int total4 = B * O / 4, n4 = O / 4;
    reduce_splitk<<<(total4 + 255) / 256, 256, 0, stream>>>(part, b2, out,
                                                            total4, n4, ZSPLIT);
}